// Round 1
// baseline (434.118 us; speedup 1.0000x reference)
//
#include <hip/hip_runtime.h>

// Problem constants (from reference): B=1, T=8192, H=400, DEPTH=32.
// Output[0, t, 0, h]   = softmax(W x_t + b)[0] * sigmoid(D . x_t)   (const over h)
// Output[0, t, 1.., h] = 0   (stack row 1 is never written in the scan, so
//                             new_top = push*pv only; rows 1..31 stay zero)
#define HDIM   400
#define TLEN   8192
#define DEPTH  32
#define SLICE4 ((DEPTH * HDIM) / 4)   // 3200 float4 per timestep slice
#define ROW4   (HDIM / 4)             // 100 float4 of val in row 0
#define BLOCK  256

// One block per timestep t. Phase 1: block-cooperative dot products ->
// val (scalar, broadcast). Phase 2: stream the 12800-float slice with
// compile-time-offset float4 stores (mimics fillBufferAligned's pattern:
// no divide, no per-iteration branch, coalesced 1 KB wave-stores).
__global__ __launch_bounds__(BLOCK) void fused_kernel(
    const float* __restrict__ hs,   // (T, H)
    const float* __restrict__ W,    // (3, H)
    const float* __restrict__ b,    // (3,)
    const float* __restrict__ D,    // (H,)
    float4* __restrict__ out)       // (T, DEPTH*H/4) float4
{
    const int t    = blockIdx.x;
    const int tid  = threadIdx.x;
    const int wave = tid >> 6;
    const int lane = tid & 63;

    const float* __restrict__ x = hs + (size_t)t * HDIM;

    // --- Phase 1: val[t] ---------------------------------------------------
    float a0 = 0.f, a1 = 0.f, a2 = 0.f, ad = 0.f;
    for (int i = tid; i < HDIM; i += BLOCK) {   // 1-2 iterations per thread
        float h = x[i];
        a0 = fmaf(h, W[i],            a0);
        a1 = fmaf(h, W[HDIM + i],     a1);
        a2 = fmaf(h, W[2 * HDIM + i], a2);
        ad = fmaf(h, D[i],            ad);
    }
    // XOR butterfly within each wave: all lanes hold the wave total.
    #pragma unroll
    for (int off = 32; off > 0; off >>= 1) {
        a0 += __shfl_xor(a0, off);
        a1 += __shfl_xor(a1, off);
        a2 += __shfl_xor(a2, off);
        ad += __shfl_xor(ad, off);
    }
    // Cross-wave reduce through LDS (4 waves).
    __shared__ float red[4][BLOCK / 64];
    if (lane == 0) {
        red[0][wave] = a0; red[1][wave] = a1;
        red[2][wave] = a2; red[3][wave] = ad;
    }
    __syncthreads();
    a0 = red[0][0] + red[0][1] + red[0][2] + red[0][3];
    a1 = red[1][0] + red[1][1] + red[1][2] + red[1][3];
    a2 = red[2][0] + red[2][1] + red[2][2] + red[2][3];
    ad = red[3][0] + red[3][1] + red[3][2] + red[3][3];

    float l0 = a0 + b[0];
    float l1 = a1 + b[1];
    float l2 = a2 + b[2];
    float m  = fmaxf(l0, fmaxf(l1, l2));
    float e0 = __expf(l0 - m);
    float e1 = __expf(l1 - m);
    float e2 = __expf(l2 - m);
    float v  = (e0 / (e0 + e1 + e2)) / (1.f + __expf(-ad));

    // --- Phase 2: stream the slice ----------------------------------------
    float4* __restrict__ o = out + (size_t)t * SLICE4;
    const float4 z4 = make_float4(0.f, 0.f, 0.f, 0.f);
    const float4 v4 = make_float4(v, v, v, v);

    // j = tid covers [0,256): the only chunk containing row 0 (first 100 f4).
    o[tid] = (tid < ROW4) ? v4 : z4;
    // Chunks [256, 3072): pure zero stores, compile-time strides.
    #pragma unroll
    for (int k = 1; k < SLICE4 / BLOCK; ++k)        // k = 1..11
        o[tid + k * BLOCK] = z4;
    // Tail [3072, 3200): 128 float4.
    if (tid < SLICE4 - (SLICE4 / BLOCK) * BLOCK)
        o[tid + (SLICE4 / BLOCK) * BLOCK] = z4;
}

extern "C" void kernel_launch(void* const* d_in, const int* in_sizes, int n_in,
                              void* d_out, int out_size, void* d_ws, size_t ws_size,
                              hipStream_t stream) {
    const float* hs = (const float*)d_in[0];  // (1, 8192, 400)
    const float* W  = (const float*)d_in[1];  // (3, 400)
    const float* b  = (const float*)d_in[2];  // (3,)
    const float* D  = (const float*)d_in[3];  // (1, 400)
    float4* out = (float4*)d_out;             // (1, 8192, 32, 400)

    fused_kernel<<<TLEN, BLOCK, 0, stream>>>(hs, W, b, D, out);
}

// Round 3
// 429.888 us; speedup vs baseline: 1.0098x; 1.0098x over previous
//
#include <hip/hip_runtime.h>

// Problem constants (from reference): B=1, T=8192, H=400, DEPTH=32.
// Output[0, t, 0, h]   = softmax(W x_t + b)[0] * sigmoid(D . x_t)   (const over h)
// Output[0, t, 1.., h] = 0  (row 1 of the stack is never written by the scan,
//                            so new_top = push*pv only; rows 1..31 stay zero)
#define HDIM   400
#define TLEN   8192
#define DEPTH  32
#define SLICE4 ((DEPTH * HDIM) / 4)   // 3200 float4 per timestep slice
#define ROW4   (HDIM / 4)             // 100 float4 of val in row 0
#define BLOCK  256
#define NCHUNK (SLICE4 / BLOCK)       // 12 full chunks + 128 tail

// Native clang vector type: __builtin_nontemporal_store requires a real
// vector type, not HIP's HIP_vector_type<float,4> class.
typedef float floatx4 __attribute__((ext_vector_type(4)));

// One block per timestep t.
//   Phase A: issue input loads (x, W, D rows) into registers.
//   Phase B: issue ALL zero stores (rows 1..31 + zero part of row 0) as
//            nontemporal stores — independent of phase A, so the store pipe
//            streams while the HBM load latency (~900 cyc) is outstanding.
//   Phase C: reduce, compute val, store row 0 (nontemporal).
// Nontemporal stores bypass L2/L3 allocation: the 419 MB output stream does
// not fit the 256 MB Infinity Cache, so allocating it only causes evict
// traffic. fillBufferAligned sustains 6.2 TB/s on this exact buffer.
__global__ __launch_bounds__(BLOCK) void fused_kernel(
    const float* __restrict__ hs,   // (T, H)
    const float* __restrict__ W,    // (3, H)
    const float* __restrict__ b,    // (3,)
    const float* __restrict__ D,    // (H,)
    floatx4* __restrict__ out)      // (T, DEPTH*H/4) float4
{
    const int t    = blockIdx.x;
    const int tid  = threadIdx.x;
    const int wave = tid >> 6;
    const int lane = tid & 63;

    const float* __restrict__ x = hs + (size_t)t * HDIM;
    floatx4* __restrict__ o = out + (size_t)t * SLICE4;
    const floatx4 z4 = (floatx4){0.f, 0.f, 0.f, 0.f};

    // --- Phase A: issue loads (no use yet -> no waitcnt before stores) -----
    const float h0  = x[tid];
    const float w00 = W[tid];
    const float w10 = W[HDIM + tid];
    const float w20 = W[2 * HDIM + tid];
    const float d0  = D[tid];
    const int   i2  = tid + BLOCK;             // second element: tid < 144
    const bool  has2 = (i2 < HDIM);
    float h1 = 0.f, w01 = 0.f, w11 = 0.f, w21 = 0.f, d1 = 0.f;
    if (has2) {
        h1  = x[i2];
        w01 = W[i2];
        w11 = W[HDIM + i2];
        w21 = W[2 * HDIM + i2];
        d1  = D[i2];
    }

    // --- Phase B: zero stores, independent of the loads above --------------
    if (tid >= ROW4) __builtin_nontemporal_store(z4, &o[tid]);   // rest of chunk 0
    #pragma unroll
    for (int k = 1; k < NCHUNK; ++k)                             // chunks 1..11
        __builtin_nontemporal_store(z4, &o[tid + k * BLOCK]);
    if (tid < SLICE4 - NCHUNK * BLOCK)                           // tail 128
        __builtin_nontemporal_store(z4, &o[tid + NCHUNK * BLOCK]);

    // --- Phase C: reduce + val + row-0 store -------------------------------
    float a0 = fmaf(h0, w00, h1 * w01);
    float a1 = fmaf(h0, w10, h1 * w11);
    float a2 = fmaf(h0, w20, h1 * w21);
    float ad = fmaf(h0, d0,  h1 * d1);

    #pragma unroll
    for (int off = 32; off > 0; off >>= 1) {
        a0 += __shfl_xor(a0, off);
        a1 += __shfl_xor(a1, off);
        a2 += __shfl_xor(a2, off);
        ad += __shfl_xor(ad, off);
    }

    __shared__ float red[4][BLOCK / 64];
    if (lane == 0) {
        red[0][wave] = a0; red[1][wave] = a1;
        red[2][wave] = a2; red[3][wave] = ad;
    }
    __syncthreads();
    a0 = red[0][0] + red[0][1] + red[0][2] + red[0][3];
    a1 = red[1][0] + red[1][1] + red[1][2] + red[1][3];
    a2 = red[2][0] + red[2][1] + red[2][2] + red[2][3];
    ad = red[3][0] + red[3][1] + red[3][2] + red[3][3];

    const float l0 = a0 + b[0];
    const float l1 = a1 + b[1];
    const float l2 = a2 + b[2];
    const float m  = fmaxf(l0, fmaxf(l1, l2));
    const float e0 = __expf(l0 - m);
    const float e1 = __expf(l1 - m);
    const float e2 = __expf(l2 - m);
    const float v  = (e0 / (e0 + e1 + e2)) / (1.f + __expf(-ad));

    if (tid < ROW4) {
        const floatx4 v4 = (floatx4){v, v, v, v};
        __builtin_nontemporal_store(v4, &o[tid]);
    }
}

extern "C" void kernel_launch(void* const* d_in, const int* in_sizes, int n_in,
                              void* d_out, int out_size, void* d_ws, size_t ws_size,
                              hipStream_t stream) {
    const float* hs = (const float*)d_in[0];  // (1, 8192, 400)
    const float* W  = (const float*)d_in[1];  // (3, 400)
    const float* b  = (const float*)d_in[2];  // (3,)
    const float* D  = (const float*)d_in[3];  // (1, 400)
    floatx4* out = (floatx4*)d_out;           // (1, 8192, 32, 400)

    fused_kernel<<<TLEN, BLOCK, 0, stream>>>(hs, W, b, D, out);
}

// Round 4
// 420.116 us; speedup vs baseline: 1.0333x; 1.0233x over previous
//
#include <hip/hip_runtime.h>

// Problem constants (from reference): B=1, T=8192, H=400, DEPTH=32.
// Output[0, t, 0, h]   = softmax(W x_t + b)[0] * sigmoid(D . x_t)   (const over h)
// Output[0, t, 1.., h] = 0  (row 1 of the stack is never written by the scan,
//                            so new_top = push*pv only; rows 1..31 stay zero)
//
// Strategy this round (discriminating experiment):
//   1. hipMemsetAsync zeroes the whole 419 MB output. This dispatches
//      __amd_rocclr_fillBufferAligned — the exact kernel rocprof shows
//      sustaining 6.2 TB/s on this buffer (≈68 µs for 419 MB). Our own
//      store loops never beat ~2.9 TB/s implied; use the proven path.
//   2. A tiny kernel computes val[t] per wave and overwrites row 0 only
//      (8192 × 1600 B = 13.1 MB ≈ a few µs).
#define HDIM   400
#define TLEN   8192
#define DEPTH  32
#define SLICE  (DEPTH * HDIM)         // 12800 floats per timestep slice
#define SLICE4 (SLICE / 4)            // 3200 float4
#define ROW4   (HDIM / 4)             // 100 float4 in row 0
#define BLOCK  256

typedef float floatx4 __attribute__((ext_vector_type(4)));

// One wave (64 lanes) per timestep t: dot products -> butterfly ->
// all lanes hold val -> write the 100 float4 of row 0.
__global__ __launch_bounds__(BLOCK) void val_row0_kernel(
    const float* __restrict__ hs,   // (T, H)
    const float* __restrict__ W,    // (3, H)
    const float* __restrict__ b,    // (3,)
    const float* __restrict__ D,    // (H,)
    floatx4* __restrict__ out)      // (T, SLICE4)
{
    const int wave = threadIdx.x >> 6;
    const int lane = threadIdx.x & 63;
    const int t = blockIdx.x * (BLOCK / 64) + wave;

    const float* __restrict__ x = hs + (size_t)t * HDIM;

    float a0 = 0.f, a1 = 0.f, a2 = 0.f, ad = 0.f;
    for (int i = lane; i < HDIM; i += 64) {
        const float h = x[i];
        a0 = fmaf(h, W[i],            a0);
        a1 = fmaf(h, W[HDIM + i],     a1);
        a2 = fmaf(h, W[2 * HDIM + i], a2);
        ad = fmaf(h, D[i],            ad);
    }

    // XOR butterfly: every lane ends with the full 64-lane totals.
    #pragma unroll
    for (int off = 32; off > 0; off >>= 1) {
        a0 += __shfl_xor(a0, off);
        a1 += __shfl_xor(a1, off);
        a2 += __shfl_xor(a2, off);
        ad += __shfl_xor(ad, off);
    }

    const float l0 = a0 + b[0];
    const float l1 = a1 + b[1];
    const float l2 = a2 + b[2];
    const float m  = fmaxf(l0, fmaxf(l1, l2));
    const float e0 = __expf(l0 - m);
    const float e1 = __expf(l1 - m);
    const float e2 = __expf(l2 - m);
    const float v  = (e0 / (e0 + e1 + e2)) / (1.f + __expf(-ad));

    // Row 0: 100 float4, written by all 64 lanes (+ lanes 0..35 again).
    floatx4* __restrict__ o = out + (size_t)t * SLICE4;
    const floatx4 v4 = (floatx4){v, v, v, v};
    o[lane] = v4;
    if (lane < ROW4 - 64) o[64 + lane] = v4;
}

extern "C" void kernel_launch(void* const* d_in, const int* in_sizes, int n_in,
                              void* d_out, int out_size, void* d_ws, size_t ws_size,
                              hipStream_t stream) {
    const float* hs = (const float*)d_in[0];  // (1, 8192, 400)
    const float* W  = (const float*)d_in[1];  // (3, 400)
    const float* b  = (const float*)d_in[2];  // (3,)
    const float* D  = (const float*)d_in[3];  // (1, 400)
    floatx4* out = (floatx4*)d_out;           // (1, 8192, 32, 400)

    // Zero the whole output via the runtime's optimized fill path
    // (graph-capturable; same kernel the harness's own reset uses).
    hipMemsetAsync(d_out, 0, (size_t)TLEN * SLICE * sizeof(float), stream);

    // Then overwrite row 0 of each slice with val[t].
    val_row0_kernel<<<TLEN / (BLOCK / 64), BLOCK, 0, stream>>>(hs, W, b, D, out);
}